// Round 4
// baseline (665.119 us; speedup 1.0000x reference)
//
#include <hip/hip_runtime.h>
#include <hip/hip_bf16.h>

#define N_NODES   100000
#define N_EDGES   1000000
#define N_FEAT    136
#define HIDDEN    64
#define N_CLASSES 2
#define NUM_GRAPHS 512

#define NP_PAD    100352          // 98 * 1024
#define SCAN_BLKS 98

// ============================ CSR build =====================================
__global__ __launch_bounds__(256) void hist_kernel(const int* __restrict__ dst,
                                                   int* __restrict__ cnt) {
    int e = blockIdx.x * 256 + threadIdx.x;
    if (e < N_EDGES) atomicAdd(&cnt[dst[e]], 1);
}

__global__ __launch_bounds__(256) void scan1_kernel(const int* __restrict__ cnt,
                                                    int* __restrict__ row_ptr,
                                                    int* __restrict__ partials) {
    __shared__ int sd[256];
    int b = blockIdx.x, t = threadIdx.x;
    int i0 = b * 1024 + t * 4;
    int c0 = (i0 + 0 < N_NODES) ? cnt[i0 + 0] : 0;
    int c1 = (i0 + 1 < N_NODES) ? cnt[i0 + 1] : 0;
    int c2 = (i0 + 2 < N_NODES) ? cnt[i0 + 2] : 0;
    int c3 = (i0 + 3 < N_NODES) ? cnt[i0 + 3] : 0;
    int tsum = c0 + c1 + c2 + c3;
    sd[t] = tsum;
    __syncthreads();
    for (int off = 1; off < 256; off <<= 1) {
        int v = (t >= off) ? sd[t - off] : 0;
        __syncthreads();
        sd[t] += v;
        __syncthreads();
    }
    int excl = sd[t] - tsum;
    row_ptr[i0 + 0] = excl;
    row_ptr[i0 + 1] = excl + c0;
    row_ptr[i0 + 2] = excl + c0 + c1;
    row_ptr[i0 + 3] = excl + c0 + c1 + c2;
    if (t == 255) partials[b] = sd[255];
}

__global__ __launch_bounds__(128) void scan2_kernel(int* __restrict__ partials) {
    __shared__ int sd[128];
    int t = threadIdx.x;
    int v = (t < SCAN_BLKS) ? partials[t] : 0;
    sd[t] = v;
    __syncthreads();
    for (int off = 1; off < 128; off <<= 1) {
        int u = (t >= off) ? sd[t - off] : 0;
        __syncthreads();
        sd[t] += u;
        __syncthreads();
    }
    partials[t] = sd[t] - v;
}

__global__ __launch_bounds__(256) void scan3_kernel(int* __restrict__ row_ptr,
                                                    int* __restrict__ cursor,
                                                    const int* __restrict__ partials) {
    int i = blockIdx.x * 256 + threadIdx.x;
    if (i < N_NODES) {
        int v = row_ptr[i] + partials[i >> 10];
        row_ptr[i] = v;
        cursor[i]  = v;
    }
    if (i == N_NODES) row_ptr[N_NODES] = N_EDGES;
}

__global__ __launch_bounds__(256) void scatter_kernel(const int* __restrict__ src,
                                                      const int* __restrict__ dst,
                                                      int* __restrict__ cursor,
                                                      int* __restrict__ csr_src) {
    int e = blockIdx.x * 256 + threadIdx.x;
    if (e < N_EDGES) {
        int pos = atomicAdd(&cursor[dst[e]], 1);
        csr_src[pos] = src[e];
    }
}

__global__ __launch_bounds__(256) void dinv_kernel(const int* __restrict__ row_ptr,
                                                   float* __restrict__ dinv) {
    int i = blockIdx.x * 256 + threadIdx.x;
    if (i < N_NODES)
        dinv[i] = rsqrtf((float)(row_ptr[i + 1] - row_ptr[i] + 1));  // +1 self-loop
}

// zero the sentinel row tp[N_NODES] (gather target for padded lanes)
__global__ __launch_bounds__(64) void zrow_kernel(float* __restrict__ tp) {
    tp[(size_t)N_NODES * HIDDEN + threadIdx.x] = 0.0f;
}

// ==================== t' = (x @ W1) * dinv  (136 -> 64) =====================
__global__ __launch_bounds__(256) void mm1_kernel(const float* __restrict__ x,
                                                  const float* __restrict__ W1,
                                                  const float* __restrict__ dinv,
                                                  float* __restrict__ tp) {
    __shared__ float Ws[N_FEAT * HIDDEN];        // 34816 B
    __shared__ float4 xs4[16][N_FEAT / 4];       // 8704 B
    int t = threadIdx.x;
    int n0 = blockIdx.x * 16;                    // 6250*16 = 100000 exact
    {
        const float4* W14 = (const float4*)W1;
        float4* Ws4 = (float4*)Ws;
        for (int i = t; i < N_FEAT * HIDDEN / 4; i += 256) Ws4[i] = W14[i];
        const float4* x4 = (const float4*)x;
        for (int i = t; i < 16 * (N_FEAT / 4); i += 256) {
            int r = i / (N_FEAT / 4), c = i % (N_FEAT / 4);
            xs4[r][c] = x4[(long long)(n0 + r) * (N_FEAT / 4) + c];
        }
    }
    __syncthreads();
    int f = t & 63, w = t >> 6;
    float a0 = 0.f, a1 = 0.f, a2 = 0.f, a3 = 0.f;
#pragma unroll 2
    for (int k4 = 0; k4 < N_FEAT / 4; ++k4) {
        float w0 = Ws[(4 * k4 + 0) * 64 + f];
        float w1 = Ws[(4 * k4 + 1) * 64 + f];
        float w2 = Ws[(4 * k4 + 2) * 64 + f];
        float w3 = Ws[(4 * k4 + 3) * 64 + f];
        float4 v;
        v = xs4[w][k4];      a0 += v.x * w0 + v.y * w1 + v.z * w2 + v.w * w3;
        v = xs4[w + 4][k4];  a1 += v.x * w0 + v.y * w1 + v.z * w2 + v.w * w3;
        v = xs4[w + 8][k4];  a2 += v.x * w0 + v.y * w1 + v.z * w2 + v.w * w3;
        v = xs4[w + 12][k4]; a3 += v.x * w0 + v.y * w1 + v.z * w2 + v.w * w3;
    }
    tp[(n0 + w) * 64 + f]      = a0 * dinv[n0 + w];
    tp[(n0 + w + 4) * 64 + f]  = a1 * dinv[n0 + w + 4];
    tp[(n0 + w + 8) * 64 + f]  = a2 * dinv[n0 + w + 8];
    tp[(n0 + w + 12) * 64 + f] = a3 * dinv[n0 + w + 12];
}

// ==================== t' = (h @ W2) * dinv  (64 -> 64) ======================
__global__ __launch_bounds__(256) void mm2_kernel(const float* __restrict__ h,
                                                  const float* __restrict__ W2,
                                                  const float* __restrict__ dinv,
                                                  float* __restrict__ tp) {
    __shared__ float Ws[HIDDEN * HIDDEN];
    __shared__ float4 hs4[16][HIDDEN / 4];
    int t = threadIdx.x;
    int n0 = blockIdx.x * 16;
    {
        const float4* W24 = (const float4*)W2;
        float4* Ws4 = (float4*)Ws;
        for (int i = t; i < HIDDEN * HIDDEN / 4; i += 256) Ws4[i] = W24[i];
        const float4* h4 = (const float4*)h;
        for (int i = t; i < 16 * (HIDDEN / 4); i += 256) {
            int r = i / (HIDDEN / 4), c = i % (HIDDEN / 4);
            hs4[r][c] = h4[(n0 + r) * (HIDDEN / 4) + c];
        }
    }
    __syncthreads();
    int f = t & 63, w = t >> 6;
    float a0 = 0.f, a1 = 0.f, a2 = 0.f, a3 = 0.f;
#pragma unroll 4
    for (int k4 = 0; k4 < HIDDEN / 4; ++k4) {
        float w0 = Ws[(4 * k4 + 0) * 64 + f];
        float w1 = Ws[(4 * k4 + 1) * 64 + f];
        float w2 = Ws[(4 * k4 + 2) * 64 + f];
        float w3 = Ws[(4 * k4 + 3) * 64 + f];
        float4 v;
        v = hs4[w][k4];      a0 += v.x * w0 + v.y * w1 + v.z * w2 + v.w * w3;
        v = hs4[w + 4][k4];  a1 += v.x * w0 + v.y * w1 + v.z * w2 + v.w * w3;
        v = hs4[w + 8][k4];  a2 += v.x * w0 + v.y * w1 + v.z * w2 + v.w * w3;
        v = hs4[w + 12][k4]; a3 += v.x * w0 + v.y * w1 + v.z * w2 + v.w * w3;
    }
    tp[(n0 + w) * 64 + f]      = a0 * dinv[n0 + w];
    tp[(n0 + w + 4) * 64 + f]  = a1 * dinv[n0 + w + 4];
    tp[(n0 + w + 8) * 64 + f]  = a2 * dinv[n0 + w + 8];
    tp[(n0 + w + 12) * 64 + f] = a3 * dinv[n0 + w + 12];
}

// ========== fused gather-aggregate + self-loop + bias + ReLU (+pool) ========
// one wave per dst node; 4 neighbor-slots x float4 lanes; sentinel row = zeros
__global__ __launch_bounds__(256) void agg_kernel(const int* __restrict__ row_ptr,
                                                  const int* __restrict__ csr_src,
                                                  const float* __restrict__ tp,
                                                  const float* __restrict__ dinv,
                                                  const float* __restrict__ bias,
                                                  float* __restrict__ hout,
                                                  const int* __restrict__ batch,
                                                  float* __restrict__ sums,
                                                  float* __restrict__ gcount,
                                                  int do_pool) {
    const float4* tp4 = (const float4*)tp;
    int lane = threadIdx.x & 63;
    int w    = threadIdx.x >> 6;
    int slot = lane >> 4;          // 0..3: which neighbor this lane group gathers
    int f4   = lane & 15;          // float4 index within the 64-float row
    int d = blockIdx.x * 4 + w;    // 25000*4 = 100000 exact

    int row = row_ptr[d], end = row_ptr[d + 1];
    // self-loop term counted once (slot 0 only)
    float4 self = tp4[d * 16 + f4];
    float4 acc;
    acc.x = (slot == 0) ? self.x : 0.f;
    acc.y = (slot == 0) ? self.y : 0.f;
    acc.z = (slot == 0) ? self.z : 0.f;
    acc.w = (slot == 0) ? self.w : 0.f;

    for (int base = row; base < end; base += 64) {
        int cnt = end - base; if (cnt > 64) cnt = 64;
        // invalid lanes carry the sentinel (zero) row index -> no predication below
        int idx = (lane < cnt) ? csr_src[base + lane] : N_NODES;
        for (int j = 0; j < cnt; j += 8) {           // j <= 56, so j+4+slot <= 63
            int s0 = __shfl(idx, j + slot);
            int s1 = __shfl(idx, j + 4 + slot);
            float4 v0 = tp4[s0 * 16 + f4];
            float4 v1 = tp4[s1 * 16 + f4];
            acc.x += v0.x; acc.y += v0.y; acc.z += v0.z; acc.w += v0.w;
            acc.x += v1.x; acc.y += v1.y; acc.z += v1.z; acc.w += v1.w;
        }
    }
    // cross-slot reduction (lanes +-16, +-32)
    acc.x += __shfl_xor(acc.x, 16); acc.y += __shfl_xor(acc.y, 16);
    acc.z += __shfl_xor(acc.z, 16); acc.w += __shfl_xor(acc.w, 16);
    acc.x += __shfl_xor(acc.x, 32); acc.y += __shfl_xor(acc.y, 32);
    acc.z += __shfl_xor(acc.z, 32); acc.w += __shfl_xor(acc.w, 32);

    if (slot == 0) {
        float di = dinv[d];
        float4 b4 = ((const float4*)bias)[f4];
        float4 h;
        h.x = fmaxf(fmaf(di, acc.x, b4.x), 0.f);
        h.y = fmaxf(fmaf(di, acc.y, b4.y), 0.f);
        h.z = fmaxf(fmaf(di, acc.z, b4.z), 0.f);
        h.w = fmaxf(fmaf(di, acc.w, b4.w), 0.f);
        ((float4*)hout)[d * 16 + f4] = h;
        if (do_pool) {
            int g = batch[d];
            float* sg = sums + g * 64 + f4 * 4;
            atomicAdd(sg + 0, h.x);
            atomicAdd(sg + 1, h.y);
            atomicAdd(sg + 2, h.z);
            atomicAdd(sg + 3, h.w);
            if (lane == 0) atomicAdd(&gcount[g], 1.0f);
        }
    }
}

// ---- head: out = (sums/counts) @ Wout + bout -------------------------------
__global__ __launch_bounds__(256) void out_kernel(const float* __restrict__ sums,
                                                  const float* __restrict__ gcount,
                                                  const float* __restrict__ Wout,
                                                  const float* __restrict__ bout,
                                                  float* __restrict__ out) {
    int idx = blockIdx.x * 256 + threadIdx.x;
    if (idx >= NUM_GRAPHS * N_CLASSES) return;
    int g = idx / N_CLASSES, c = idx % N_CLASSES;
    float inv_cnt = 1.0f / fmaxf(gcount[g], 1.0f);
    float acc = 0.0f;
#pragma unroll
    for (int k = 0; k < HIDDEN; ++k)
        acc += sums[g * HIDDEN + k] * Wout[k * N_CLASSES + c];
    out[idx] = acc * inv_cnt + bout[c];
}

extern "C" void kernel_launch(void* const* d_in, const int* in_sizes, int n_in,
                              void* d_out, int out_size, void* d_ws, size_t ws_size,
                              hipStream_t stream) {
    const float* x     = (const float*)d_in[0];
    const int*   ei    = (const int*)d_in[1];
    const int*   batch = (const int*)d_in[2];
    const float* W1    = (const float*)d_in[3];
    const float* b1    = (const float*)d_in[4];
    const float* W2    = (const float*)d_in[5];
    const float* b2    = (const float*)d_in[6];
    const float* Wout  = (const float*)d_in[7];
    const float* bout  = (const float*)d_in[8];
    float* out = (float*)d_out;

    const int* src = ei;
    const int* dst = ei + N_EDGES;

    // -------- workspace layout (~57 MB) --------
    char* p = (char*)d_ws;
    int*   row_ptr  = (int*)p;        p += (NP_PAD + 256) * sizeof(int);
    int*   cnt      = (int*)p;        p += NP_PAD * sizeof(int);   // hist, then cursor
    int*   partials = (int*)p;        p += 256 * sizeof(int);
    int*   csr_src  = (int*)p;        p += (size_t)N_EDGES * sizeof(int);
    float* dinv     = (float*)p;      p += NP_PAD * sizeof(float);
    float* bufA     = (float*)p;      p += (size_t)(N_NODES + 1) * HIDDEN * sizeof(float); // +sentinel
    float* bufB     = (float*)p;      p += (size_t)N_NODES * HIDDEN * sizeof(float);
    float* sums     = (float*)p;      p += NUM_GRAPHS * HIDDEN * sizeof(float);
    float* gcount   = (float*)p;      p += NUM_GRAPHS * sizeof(float);

    const int NB_E  = (N_EDGES + 255) / 256;
    const int NB_N  = (N_NODES + 255) / 256;
    const int NB_MM = N_NODES / 16;          // 6250
    const int NB_AG = N_NODES / 4;           // 25000

    // -------- CSR build --------
    hipMemsetAsync(cnt, 0, NP_PAD * sizeof(int), stream);
    hist_kernel<<<NB_E, 256, 0, stream>>>(dst, cnt);
    scan1_kernel<<<SCAN_BLKS, 256, 0, stream>>>(cnt, row_ptr, partials);
    scan2_kernel<<<1, 128, 0, stream>>>(partials);
    scan3_kernel<<<NP_PAD / 256, 256, 0, stream>>>(row_ptr, cnt, partials);
    scatter_kernel<<<NB_E, 256, 0, stream>>>(src, dst, cnt, csr_src);
    dinv_kernel<<<NB_N, 256, 0, stream>>>(row_ptr, dinv);
    zrow_kernel<<<1, 64, 0, stream>>>(bufA);

    hipMemsetAsync(sums, 0, (NUM_GRAPHS * HIDDEN + NUM_GRAPHS) * sizeof(float), stream);

    // -------- layer 1 --------
    mm1_kernel<<<NB_MM, 256, 0, stream>>>(x, W1, dinv, bufA);
    agg_kernel<<<NB_AG, 256, 0, stream>>>(row_ptr, csr_src, bufA, dinv, b1, bufB,
                                          batch, sums, gcount, 0);
    // -------- layer 2 (pool fused) --------
    mm2_kernel<<<NB_MM, 256, 0, stream>>>(bufB, W2, dinv, bufA);
    agg_kernel<<<NB_AG, 256, 0, stream>>>(row_ptr, csr_src, bufA, dinv, b2, bufB,
                                          batch, sums, gcount, 1);
    // -------- head --------
    out_kernel<<<(NUM_GRAPHS * N_CLASSES + 255) / 256, 256, 0, stream>>>(
        sums, gcount, Wout, bout, out);
}

// Round 5
// 531.075 us; speedup vs baseline: 1.2524x; 1.2524x over previous
//
#include <hip/hip_runtime.h>
#include <hip/hip_bf16.h>

#define N_NODES   100000
#define N_EDGES   1000000
#define N_FEAT    136
#define HIDDEN    64
#define N_CLASSES 2
#define NUM_GRAPHS 512

#define NP_PAD    100352          // 98 * 1024
#define SCAN_BLKS 98

typedef unsigned short ushort_t;

// fp32 -> bf16 (RTNE), bf16 -> fp32
__device__ __forceinline__ ushort_t f2b(float v) {
    unsigned b = __float_as_uint(v);
    return (ushort_t)((b + 0x7FFF + ((b >> 16) & 1)) >> 16);
}
__device__ __forceinline__ float b2f(ushort_t u) {
    return __uint_as_float(((unsigned)u) << 16);
}

// ============================ CSR build =====================================
__global__ __launch_bounds__(256) void hist_kernel(const int* __restrict__ dst,
                                                   int* __restrict__ cnt) {
    int e = blockIdx.x * 256 + threadIdx.x;
    if (e < N_EDGES) atomicAdd(&cnt[dst[e]], 1);
}

__global__ __launch_bounds__(256) void scan1_kernel(const int* __restrict__ cnt,
                                                    int* __restrict__ row_ptr,
                                                    int* __restrict__ partials) {
    __shared__ int sd[256];
    int b = blockIdx.x, t = threadIdx.x;
    int i0 = b * 1024 + t * 4;
    int c0 = (i0 + 0 < N_NODES) ? cnt[i0 + 0] : 0;
    int c1 = (i0 + 1 < N_NODES) ? cnt[i0 + 1] : 0;
    int c2 = (i0 + 2 < N_NODES) ? cnt[i0 + 2] : 0;
    int c3 = (i0 + 3 < N_NODES) ? cnt[i0 + 3] : 0;
    int tsum = c0 + c1 + c2 + c3;
    sd[t] = tsum;
    __syncthreads();
    for (int off = 1; off < 256; off <<= 1) {
        int v = (t >= off) ? sd[t - off] : 0;
        __syncthreads();
        sd[t] += v;
        __syncthreads();
    }
    int excl = sd[t] - tsum;
    row_ptr[i0 + 0] = excl;
    row_ptr[i0 + 1] = excl + c0;
    row_ptr[i0 + 2] = excl + c0 + c1;
    row_ptr[i0 + 3] = excl + c0 + c1 + c2;
    if (t == 255) partials[b] = sd[255];
}

__global__ __launch_bounds__(128) void scan2_kernel(int* __restrict__ partials) {
    __shared__ int sd[128];
    int t = threadIdx.x;
    int v = (t < SCAN_BLKS) ? partials[t] : 0;
    sd[t] = v;
    __syncthreads();
    for (int off = 1; off < 128; off <<= 1) {
        int u = (t >= off) ? sd[t - off] : 0;
        __syncthreads();
        sd[t] += u;
        __syncthreads();
    }
    partials[t] = sd[t] - v;
}

__global__ __launch_bounds__(256) void scan3_kernel(int* __restrict__ row_ptr,
                                                    int* __restrict__ cursor,
                                                    const int* __restrict__ partials) {
    int i = blockIdx.x * 256 + threadIdx.x;
    if (i < N_NODES) {
        int v = row_ptr[i] + partials[i >> 10];
        row_ptr[i] = v;
        cursor[i]  = v;
    }
    if (i == N_NODES) row_ptr[N_NODES] = N_EDGES;
}

__global__ __launch_bounds__(256) void scatter_kernel(const int* __restrict__ src,
                                                      const int* __restrict__ dst,
                                                      int* __restrict__ cursor,
                                                      int* __restrict__ csr_src) {
    int e = blockIdx.x * 256 + threadIdx.x;
    if (e < N_EDGES) {
        int pos = atomicAdd(&cursor[dst[e]], 1);
        csr_src[pos] = src[e];
    }
}

__global__ __launch_bounds__(256) void dinv_kernel(const int* __restrict__ row_ptr,
                                                   float* __restrict__ dinv) {
    int i = blockIdx.x * 256 + threadIdx.x;
    if (i < N_NODES)
        dinv[i] = rsqrtf((float)(row_ptr[i + 1] - row_ptr[i] + 1));  // +1 self-loop
}

// zero the bf16 sentinel row tpb[N_NODES]
__global__ __launch_bounds__(64) void zrow_kernel(ushort_t* __restrict__ tpb) {
    tpb[(size_t)N_NODES * HIDDEN + threadIdx.x] = 0;
}

// ==================== t' = (x @ W1) * dinv -> bf16  (136 -> 64) =============
__global__ __launch_bounds__(256) void mm1_kernel(const float* __restrict__ x,
                                                  const float* __restrict__ W1,
                                                  const float* __restrict__ dinv,
                                                  ushort_t* __restrict__ tpb) {
    __shared__ float Ws[N_FEAT * HIDDEN];        // 34816 B
    __shared__ float4 xs4[16][N_FEAT / 4];       // 8704 B
    int t = threadIdx.x;
    int n0 = blockIdx.x * 16;                    // 6250*16 = 100000 exact
    {
        const float4* W14 = (const float4*)W1;
        float4* Ws4 = (float4*)Ws;
        for (int i = t; i < N_FEAT * HIDDEN / 4; i += 256) Ws4[i] = W14[i];
        const float4* x4 = (const float4*)x;
        for (int i = t; i < 16 * (N_FEAT / 4); i += 256) {
            int r = i / (N_FEAT / 4), c = i % (N_FEAT / 4);
            xs4[r][c] = x4[(long long)(n0 + r) * (N_FEAT / 4) + c];
        }
    }
    __syncthreads();
    int f = t & 63, w = t >> 6;
    float a0 = 0.f, a1 = 0.f, a2 = 0.f, a3 = 0.f;
#pragma unroll 2
    for (int k4 = 0; k4 < N_FEAT / 4; ++k4) {
        float w0 = Ws[(4 * k4 + 0) * 64 + f];
        float w1 = Ws[(4 * k4 + 1) * 64 + f];
        float w2 = Ws[(4 * k4 + 2) * 64 + f];
        float w3 = Ws[(4 * k4 + 3) * 64 + f];
        float4 v;
        v = xs4[w][k4];      a0 += v.x * w0 + v.y * w1 + v.z * w2 + v.w * w3;
        v = xs4[w + 4][k4];  a1 += v.x * w0 + v.y * w1 + v.z * w2 + v.w * w3;
        v = xs4[w + 8][k4];  a2 += v.x * w0 + v.y * w1 + v.z * w2 + v.w * w3;
        v = xs4[w + 12][k4]; a3 += v.x * w0 + v.y * w1 + v.z * w2 + v.w * w3;
    }
    tpb[(n0 + w) * 64 + f]      = f2b(a0 * dinv[n0 + w]);
    tpb[(n0 + w + 4) * 64 + f]  = f2b(a1 * dinv[n0 + w + 4]);
    tpb[(n0 + w + 8) * 64 + f]  = f2b(a2 * dinv[n0 + w + 8]);
    tpb[(n0 + w + 12) * 64 + f] = f2b(a3 * dinv[n0 + w + 12]);
}

// ==================== t' = (h @ W2) * dinv -> bf16  (64 -> 64) ==============
__global__ __launch_bounds__(256) void mm2_kernel(const float* __restrict__ h,
                                                  const float* __restrict__ W2,
                                                  const float* __restrict__ dinv,
                                                  ushort_t* __restrict__ tpb) {
    __shared__ float Ws[HIDDEN * HIDDEN];
    __shared__ float4 hs4[16][HIDDEN / 4];
    int t = threadIdx.x;
    int n0 = blockIdx.x * 16;
    {
        const float4* W24 = (const float4*)W2;
        float4* Ws4 = (float4*)Ws;
        for (int i = t; i < HIDDEN * HIDDEN / 4; i += 256) Ws4[i] = W24[i];
        const float4* h4 = (const float4*)h;
        for (int i = t; i < 16 * (HIDDEN / 4); i += 256) {
            int r = i / (HIDDEN / 4), c = i % (HIDDEN / 4);
            hs4[r][c] = h4[(n0 + r) * (HIDDEN / 4) + c];
        }
    }
    __syncthreads();
    int f = t & 63, w = t >> 6;
    float a0 = 0.f, a1 = 0.f, a2 = 0.f, a3 = 0.f;
#pragma unroll 4
    for (int k4 = 0; k4 < HIDDEN / 4; ++k4) {
        float w0 = Ws[(4 * k4 + 0) * 64 + f];
        float w1 = Ws[(4 * k4 + 1) * 64 + f];
        float w2 = Ws[(4 * k4 + 2) * 64 + f];
        float w3 = Ws[(4 * k4 + 3) * 64 + f];
        float4 v;
        v = hs4[w][k4];      a0 += v.x * w0 + v.y * w1 + v.z * w2 + v.w * w3;
        v = hs4[w + 4][k4];  a1 += v.x * w0 + v.y * w1 + v.z * w2 + v.w * w3;
        v = hs4[w + 8][k4];  a2 += v.x * w0 + v.y * w1 + v.z * w2 + v.w * w3;
        v = hs4[w + 12][k4]; a3 += v.x * w0 + v.y * w1 + v.z * w2 + v.w * w3;
    }
    tpb[(n0 + w) * 64 + f]      = f2b(a0 * dinv[n0 + w]);
    tpb[(n0 + w + 4) * 64 + f]  = f2b(a1 * dinv[n0 + w + 4]);
    tpb[(n0 + w + 8) * 64 + f]  = f2b(a2 * dinv[n0 + w + 8]);
    tpb[(n0 + w + 12) * 64 + f] = f2b(a3 * dinv[n0 + w + 12]);
}

// ========== fused gather-aggregate + self-loop + bias + ReLU (+pool) ========
// one wave per dst node; 16-wide gather batches; sentinel row = zeros
__global__ __launch_bounds__(256) void agg_kernel(const int* __restrict__ row_ptr,
                                                  const int* __restrict__ csr_src,
                                                  const ushort_t* __restrict__ tpb,
                                                  const float* __restrict__ dinv,
                                                  const float* __restrict__ bias,
                                                  float* __restrict__ hout,
                                                  const int* __restrict__ batch,
                                                  float* __restrict__ sums,
                                                  float* __restrict__ gcount,
                                                  int do_pool) {
    int lane = threadIdx.x & 63;
    int w    = threadIdx.x >> 6;
    int d = blockIdx.x * 4 + w;                  // 25000*4 = 100000 exact
    int f = lane;

    // issue self gather + row_ptr loads immediately (overlap)
    float acc = b2f(tpb[d * 64 + f]);            // self-loop term
    int row = row_ptr[d], deg = row_ptr[d + 1] - row;

    for (int base = 0; base < deg; base += 64) {
        int cnt = deg - base; if (cnt > 64) cnt = 64;
        // invalid lanes carry the sentinel (zero) row -> no predication in gathers
        int idx = (lane < cnt) ? csr_src[row + base + lane] : N_NODES;
        int cnt16 = (cnt + 15) & ~15;            // pad to x16 with sentinel lanes
        for (int j = 0; j < cnt16; j += 16) {
            int ss[16];
#pragma unroll
            for (int k = 0; k < 16; ++k) ss[k] = __shfl(idx, j + k);
            float vv[16];
#pragma unroll
            for (int k = 0; k < 16; ++k) vv[k] = b2f(tpb[ss[k] * 64 + f]);
#pragma unroll
            for (int k = 0; k < 16; ++k) acc += vv[k];
        }
    }

    float h = fmaxf(fmaf(dinv[d], acc, bias[f]), 0.0f);
    if (!do_pool) {
        hout[d * 64 + f] = h;
    } else {
        int g = batch[d];
        atomicAdd(&sums[g * 64 + f], h);
        if (f == 0) atomicAdd(&gcount[g], 1.0f);
    }
}

// ---- head: out = (sums/counts) @ Wout + bout -------------------------------
__global__ __launch_bounds__(256) void out_kernel(const float* __restrict__ sums,
                                                  const float* __restrict__ gcount,
                                                  const float* __restrict__ Wout,
                                                  const float* __restrict__ bout,
                                                  float* __restrict__ out) {
    int idx = blockIdx.x * 256 + threadIdx.x;
    if (idx >= NUM_GRAPHS * N_CLASSES) return;
    int g = idx / N_CLASSES, c = idx % N_CLASSES;
    float inv_cnt = 1.0f / fmaxf(gcount[g], 1.0f);
    float acc = 0.0f;
#pragma unroll
    for (int k = 0; k < HIDDEN; ++k)
        acc += sums[g * HIDDEN + k] * Wout[k * N_CLASSES + c];
    out[idx] = acc * inv_cnt + bout[c];
}

extern "C" void kernel_launch(void* const* d_in, const int* in_sizes, int n_in,
                              void* d_out, int out_size, void* d_ws, size_t ws_size,
                              hipStream_t stream) {
    const float* x     = (const float*)d_in[0];
    const int*   ei    = (const int*)d_in[1];
    const int*   batch = (const int*)d_in[2];
    const float* W1    = (const float*)d_in[3];
    const float* b1    = (const float*)d_in[4];
    const float* W2    = (const float*)d_in[5];
    const float* b2    = (const float*)d_in[6];
    const float* Wout  = (const float*)d_in[7];
    const float* bout  = (const float*)d_in[8];
    float* out = (float*)d_out;

    const int* src = ei;
    const int* dst = ei + N_EDGES;

    // -------- workspace layout (~45 MB) --------
    char* p = (char*)d_ws;
    int*      row_ptr  = (int*)p;      p += (NP_PAD + 256) * sizeof(int);
    int*      cnt      = (int*)p;      p += NP_PAD * sizeof(int);   // hist, then cursor
    int*      partials = (int*)p;      p += 256 * sizeof(int);
    int*      csr_src  = (int*)p;      p += (size_t)N_EDGES * sizeof(int);
    float*    dinv     = (float*)p;    p += NP_PAD * sizeof(float);
    ushort_t* tpb      = (ushort_t*)p; p += (size_t)(N_NODES + 1) * HIDDEN * sizeof(ushort_t);
    float*    hbuf     = (float*)p;    p += (size_t)N_NODES * HIDDEN * sizeof(float);
    float*    sums     = (float*)p;    p += NUM_GRAPHS * HIDDEN * sizeof(float);
    float*    gcount   = (float*)p;    p += NUM_GRAPHS * sizeof(float);

    const int NB_E  = (N_EDGES + 255) / 256;
    const int NB_N  = (N_NODES + 255) / 256;
    const int NB_MM = N_NODES / 16;          // 6250
    const int NB_AG = N_NODES / 4;           // 25000

    // -------- CSR build --------
    hipMemsetAsync(cnt, 0, NP_PAD * sizeof(int), stream);
    hist_kernel<<<NB_E, 256, 0, stream>>>(dst, cnt);
    scan1_kernel<<<SCAN_BLKS, 256, 0, stream>>>(cnt, row_ptr, partials);
    scan2_kernel<<<1, 128, 0, stream>>>(partials);
    scan3_kernel<<<NP_PAD / 256, 256, 0, stream>>>(row_ptr, cnt, partials);
    scatter_kernel<<<NB_E, 256, 0, stream>>>(src, dst, cnt, csr_src);
    dinv_kernel<<<NB_N, 256, 0, stream>>>(row_ptr, dinv);
    zrow_kernel<<<1, 64, 0, stream>>>(tpb);

    hipMemsetAsync(sums, 0, (NUM_GRAPHS * HIDDEN + NUM_GRAPHS) * sizeof(float), stream);

    // -------- layer 1 --------
    mm1_kernel<<<NB_MM, 256, 0, stream>>>(x, W1, dinv, tpb);
    agg_kernel<<<NB_AG, 256, 0, stream>>>(row_ptr, csr_src, tpb, dinv, b1, hbuf,
                                          batch, sums, gcount, 0);
    // -------- layer 2 (pool fused, no hout store) --------
    mm2_kernel<<<NB_MM, 256, 0, stream>>>(hbuf, W2, dinv, tpb);
    agg_kernel<<<NB_AG, 256, 0, stream>>>(row_ptr, csr_src, tpb, dinv, b2, hbuf,
                                          batch, sums, gcount, 1);
    // -------- head --------
    out_kernel<<<(NUM_GRAPHS * N_CLASSES + 255) / 256, 256, 0, stream>>>(
        sums, gcount, Wout, bout, out);
}